// Round 2
// 1377.987 us; speedup vs baseline: 1.2835x; 1.2835x over previous
//
#include <hip/hip_runtime.h>

#define NP   1000
#define CAND 128

typedef __attribute__((ext_vector_type(8))) short short8;
typedef __attribute__((ext_vector_type(4))) float f32x4;

union Frag { uint4 q; short8 v; };

__device__ __forceinline__ unsigned short f2bf(float x) {
  union { float f; unsigned u; } c; c.f = x;
  return (unsigned short)((c.u + 0x7FFFu + ((c.u >> 16) & 1u)) >> 16);
}
__device__ __forceinline__ float bf2f(unsigned short h) {
  union { unsigned u; float f; } c; c.u = ((unsigned)h) << 16; return c.f;
}
// single-instruction packed f32->bf16 (RNE), gfx950
__device__ __forceinline__ unsigned cvtpk(float a, float b) {
  unsigned r;
  asm("v_cvt_pk_bf16_f32 %0, %1, %2" : "=v"(r) : "v"(a), "v"(b));
  return r;
}
__device__ __forceinline__ float gelu_ex(float x) {
  return 0.5f * x * (1.0f + erff(x * 0.70710678118654752f));
}
// tanh-approx gelu, division-free (rcp approx) -- bf16 screening path only
__device__ __forceinline__ float gelu_fast(float x) {
  float x2 = x * x;
  float z = 1.5957691216057308f * fmaf(0.044715f * x2, x, x);
  float e = __expf(z);
  float r = __builtin_amdgcn_rcpf(e + 1.0f);
  float t = fmaf(-2.0f, r, 1.0f);      // tanh(z/2)
  float hx = 0.5f * x;
  return fmaf(hx, t, hx);
}

// ---- workspace layout (bytes) ----
constexpr size_t OFF_W1T  = 0;          // bf16 [128][64]  0.1*W_t1[:64]^T
constexpr size_t OFF_W2T  = 16384;      // bf16 [64][128]  W_t2^T
constexpr size_t OFF_W3T  = 32768;      // bf16 [64][64]   W_w1[:64]^T
constexpr size_t OFF_W1TF = 40960;      // f32  [128][64]  W_t1[:64]^T (unscaled, exact path)
constexpr size_t OFF_W3TF = 73728;      // f32  [64][64]   W_w1[:64]^T
constexpr size_t OFF_TB   = 90112;      // f32  [2048][128] transition bias
constexpr size_t OFF_WB   = 1138688;    // f32  [2048][64]  weight-net bias
constexpr size_t OFF_LOGW = 1662976;    // f32  [2048][1024] bf16-path log_w
constexpr size_t OFF_SIDX = 10051584;   // i32  [2048][128] candidate particle idx
constexpr size_t OFF_SVAL = 11100160;   // f32  [2048][128] candidate bf16-path log_w
constexpr size_t OFF_MZ   = 12148736;   // f32  [2048][2]   max, sumexp
constexpr size_t OFF_LWC  = 12165120;   // f32  [2048][128] fp32 log_w of candidates
constexpr size_t OFF_PC   = 13213696;   // f32  [2048][128][64] fp32 particles of candidates

// ================= K0: weight prep =================
__global__ __launch_bounds__(256) void k0_prep(
    const float* __restrict__ Wt1, const float* __restrict__ Wt2,
    const float* __restrict__ Ww1,
    unsigned short* __restrict__ W1T, unsigned short* __restrict__ W2T,
    unsigned short* __restrict__ W3T, float* __restrict__ W1Tf,
    float* __restrict__ W3Tf)
{
  int t = blockIdx.x * 256 + threadIdx.x;
  if (t < 8192) {
    int n = t >> 6, k = t & 63;
    // fold the 0.1 particle scale into the bf16 screening weight
    W1T[t] = f2bf(0.1f * Wt1[k * 128 + n]);
  } else if (t < 16384) {
    int u = t - 8192; int n = u >> 7, k = u & 127;
    W2T[u] = f2bf(Wt2[k * 64 + n]);
  } else if (t < 20480) {
    int u = t - 16384; int n = u >> 6, k = u & 63;
    W3T[u] = f2bf(Ww1[k * 64 + n]);
  } else if (t < 28672) {
    int u = t - 20480; int j = u >> 6, d = u & 63;
    W1Tf[u] = Wt1[d * 128 + j];          // exact path stays unscaled (bit-identical)
  } else if (t < 32768) {
    int u = t - 28672; int j = u >> 6, d = u & 63;
    W3Tf[u] = Ww1[d * 64 + j];
  }
}

// ================= K1: particle mean -> regime probs -> transition bias =================
__global__ __launch_bounds__(256) void k1_mean(
    const float* __restrict__ X, const float* __restrict__ Wr,
    const float* __restrict__ br, const float* __restrict__ Wt1,
    const float* __restrict__ bt1, float* __restrict__ tbias,
    float* __restrict__ out1)
{
  __shared__ __align__(16) float red[16][64];
  __shared__ float meanv[64];
  __shared__ float probs[4];
  __shared__ float lgs[4];
  const int tid = threadIdx.x;
  const int b = blockIdx.x;
  const int g = tid >> 4, c4 = (tid & 15) * 4;
  const float* Xb = X + (size_t)b * (NP * 64);
  float4 s = make_float4(0.f, 0.f, 0.f, 0.f);
  for (int r = g; r < NP; r += 16) {
    float4 v = *(const float4*)(Xb + r * 64 + c4);
    s.x += v.x; s.y += v.y; s.z += v.z; s.w += v.w;
  }
  *(float4*)&red[g][c4] = s;
  __syncthreads();
  if (tid < 64) {
    float t = 0.f;
    #pragma unroll
    for (int i = 0; i < 16; ++i) t += red[i][tid];
    meanv[tid] = t * (0.1f / 1000.0f);
  }
  __syncthreads();
  if (tid < 4) {
    float lg = br[tid];
    for (int d = 0; d < 64; ++d) lg += meanv[d] * Wr[d * 4 + tid];
    lgs[tid] = lg;
  }
  __syncthreads();
  if (tid < 4) {
    float l0 = lgs[0], l1 = lgs[1], l2 = lgs[2], l3 = lgs[3];
    float mx = fmaxf(fmaxf(l0, l1), fmaxf(l2, l3));
    float Zs = expf(l0 - mx) + expf(l1 - mx) + expf(l2 - mx) + expf(l3 - mx);
    float p = expf(lgs[tid] - mx) / Zs;
    probs[tid] = p;
    out1[b * 4 + tid] = p;
  }
  __syncthreads();
  if (tid < 128) {
    float t = bt1[tid];
    #pragma unroll
    for (int k = 0; k < 4; ++k) t += probs[k] * Wt1[(64 + k) * 128 + tid];
    tbias[b * 128 + tid] = t;
  }
}

// ================= K2: obs encoder -> weight-net bias =================
__global__ __launch_bounds__(128) void k2_obs(
    const float* __restrict__ obs, const float* __restrict__ W1,
    const float* __restrict__ b1, const float* __restrict__ W2,
    const float* __restrict__ b2, const float* __restrict__ Ww1,
    const float* __restrict__ bw1, float* __restrict__ wbias)
{
  __shared__ float xo[256];
  __shared__ float h[128];
  __shared__ float e[64];
  const int tid = threadIdx.x;
  const int b = blockIdx.x;
  xo[tid] = obs[b * 256 + tid];
  xo[tid + 128] = obs[b * 256 + 128 + tid];
  __syncthreads();
  {
    float acc = b1[tid];
    #pragma unroll 4
    for (int i = 0; i < 256; ++i) acc += xo[i] * W1[i * 128 + tid];
    h[tid] = gelu_ex(acc);
  }
  __syncthreads();
  if (tid < 64) {
    float a2 = b2[tid];
    #pragma unroll 4
    for (int i = 0; i < 128; ++i) a2 += h[i] * W2[i * 64 + tid];
    e[tid] = a2;
  }
  __syncthreads();
  if (tid < 64) {
    float a3 = bw1[tid];
    #pragma unroll 4
    for (int i = 0; i < 64; ++i) a3 += e[i] * Ww1[(64 + i) * 64 + tid];
    wbias[b * 64 + tid] = a3;
  }
}

// ================= K3: bf16 MFMA screening pass =================
// VALU-lean rewrite: div-free gelu, v_cvt_pk_bf16_f32 packing, X pre-packed
// to bf16 frags (0.1 folded into W1T by k0), G4 computed straight from the
// G3 accumulator registers (no H2 cvt / LDS round trip), W3 A-frags
// streamed from global (L1-resident 8KB) instead of LDS. LDS = 54272 B ->
// 3 blocks/CU; launch_bounds(256,3) matches that (VGPR cap ~170, no spill).
__global__ __launch_bounds__(256, 3) void k3_main(
    const float* __restrict__ X,
    const unsigned short* __restrict__ W1T, const unsigned short* __restrict__ W2T,
    const unsigned short* __restrict__ W3T,
    const float* __restrict__ tbias, const float* __restrict__ wbias,
    const float* __restrict__ bt2, const float* __restrict__ Ww2,
    const float* __restrict__ bw2, float* __restrict__ logw)
{
  __shared__ __align__(16) unsigned short H1s[64][136];   // 17408 B
  __shared__ __align__(16) unsigned short W1s[128][72];   // 18432 B
  __shared__ __align__(16) unsigned short W2s[64][136];   // 17408 B
  __shared__ __align__(16) float tbs[128];
  __shared__ __align__(16) float bt2s[64];
  __shared__ __align__(16) float wbs[64];

  const int tid = threadIdx.x;
  const int b = blockIdx.y;
  const int pbase = blockIdx.x * 256;

  {
    const uint4* s1 = (const uint4*)W1T;
    #pragma unroll
    for (int it = 0; it < 4; ++it) {
      int i = tid + it * 256;
      *(uint4*)&W1s[i >> 3][(i & 7) * 8] = s1[i];
    }
    const uint4* s2 = (const uint4*)W2T;
    #pragma unroll
    for (int it = 0; it < 4; ++it) {
      int i = tid + it * 256;
      *(uint4*)&W2s[i >> 4][(i & 15) * 8] = s2[i];
    }
    if (tid < 128) tbs[tid] = tbias[b * 128 + tid];
    if (tid < 64) {
      bt2s[tid] = bt2[tid];
      wbs[tid] = wbias[b * 64 + tid];
    }
  }

  const int wave = tid >> 6;
  const int lane = tid & 63;
  const int quad = lane >> 4;
  const int l15 = lane & 15;
  const int prow = wave * 16 + l15;

  const float bw2v = bw2[0];                 // uniform -> s_load
  float4 wv4[4];                             // Ww2 slice this lane needs in G4
  #pragma unroll
  for (int ct = 0; ct < 4; ++ct)
    wv4[ct] = *(const float4*)&Ww2[ct * 16 + quad * 4];

  // preload X for all 4 tiles and pack to bf16 frags immediately (16 VGPRs)
  Frag xf[4][2];
  #pragma unroll
  for (int t = 0; t < 4; ++t) {
    int gp = pbase + t * 64 + prow;
    if (gp < NP) {
      const float* xr = X + ((size_t)b * (NP * 64) + (size_t)gp * 64);
      float4 v0 = *(const float4*)(xr + quad * 8);
      float4 v1 = *(const float4*)(xr + quad * 8 + 4);
      float4 v2 = *(const float4*)(xr + 32 + quad * 8);
      float4 v3 = *(const float4*)(xr + 32 + quad * 8 + 4);
      xf[t][0].q = make_uint4(cvtpk(v0.x, v0.y), cvtpk(v0.z, v0.w),
                              cvtpk(v1.x, v1.y), cvtpk(v1.z, v1.w));
      xf[t][1].q = make_uint4(cvtpk(v2.x, v2.y), cvtpk(v2.z, v2.w),
                              cvtpk(v3.x, v3.y), cvtpk(v3.z, v3.w));
    } else {
      xf[t][0].q = make_uint4(0u, 0u, 0u, 0u);
      xf[t][1].q = make_uint4(0u, 0u, 0u, 0u);
    }
  }
  __syncthreads();

  const uint4* W3v = (const uint4*)W3T;      // [64][64] bf16 -> 512 uint4, L1-hot

  #pragma unroll
  for (int t = 0; t < 4; ++t) {
    const int gp = pbase + t * 64 + prow;
    const bool valid = gp < NP;

    // G1: H1 = gelu(0.1X @ W_t1[:64] + tbias)  (scale pre-folded into W1T)
    #pragma unroll
    for (int ct = 0; ct < 8; ++ct) {
      Frag a0, a1;
      a0.q = *(const uint4*)&W1s[ct * 16 + l15][quad * 8];
      a1.q = *(const uint4*)&W1s[ct * 16 + l15][32 + quad * 8];
      f32x4 acc = {0.f, 0.f, 0.f, 0.f};
      acc = __builtin_amdgcn_mfma_f32_16x16x32_bf16(a0.v, xf[t][0].v, acc, 0, 0, 0);
      acc = __builtin_amdgcn_mfma_f32_16x16x32_bf16(a1.v, xf[t][1].v, acc, 0, 0, 0);
      int cb = ct * 16 + quad * 4;
      float4 tb = *(const float4*)&tbs[cb];
      uint2 o;
      o.x = cvtpk(gelu_fast(acc[0] + tb.x), gelu_fast(acc[1] + tb.y));
      o.y = cvtpk(gelu_fast(acc[2] + tb.z), gelu_fast(acc[3] + tb.w));
      *(uint2*)&H1s[prow][cb] = o;
    }

    // G2: P = H1 @ W_t2 + b_t2 -> overwrite H1s cols 0..63
    Frag hb[4];
    #pragma unroll
    for (int ks = 0; ks < 4; ++ks)
      hb[ks].q = *(const uint4*)&H1s[prow][ks * 32 + quad * 8];
    #pragma unroll
    for (int ct = 0; ct < 4; ++ct) {
      f32x4 acc = {0.f, 0.f, 0.f, 0.f};
      #pragma unroll
      for (int ks = 0; ks < 4; ++ks) {
        Frag a;
        a.q = *(const uint4*)&W2s[ct * 16 + l15][ks * 32 + quad * 8];
        acc = __builtin_amdgcn_mfma_f32_16x16x32_bf16(a.v, hb[ks].v, acc, 0, 0, 0);
      }
      int cb = ct * 16 + quad * 4;
      float4 b2 = *(const float4*)&bt2s[cb];
      uint2 o;
      o.x = cvtpk(acc[0] + b2.x, acc[1] + b2.y);
      o.y = cvtpk(acc[2] + b2.z, acc[3] + b2.w);
      *(uint2*)&H1s[prow][cb] = o;
    }

    // G3+G4 fused: lane (quad,l15) holds H2 channels {ct*16+quad*4+r} of
    // particle l15 in the accumulator -> dot with Ww2 directly in fp32.
    Frag pb0, pb1;
    pb0.q = *(const uint4*)&H1s[prow][quad * 8];
    pb1.q = *(const uint4*)&H1s[prow][32 + quad * 8];
    float accw = 0.f;
    #pragma unroll
    for (int ct = 0; ct < 4; ++ct) {
      Frag a0, a1;
      a0.q = W3v[(ct * 16 + l15) * 8 + quad];
      a1.q = W3v[(ct * 16 + l15) * 8 + quad + 4];
      f32x4 acc = {0.f, 0.f, 0.f, 0.f};
      acc = __builtin_amdgcn_mfma_f32_16x16x32_bf16(a0.v, pb0.v, acc, 0, 0, 0);
      acc = __builtin_amdgcn_mfma_f32_16x16x32_bf16(a1.v, pb1.v, acc, 0, 0, 0);
      int cb = ct * 16 + quad * 4;
      float4 wb = *(const float4*)&wbs[cb];
      accw = fmaf(gelu_fast(acc[0] + wb.x), wv4[ct].x, accw);
      accw = fmaf(gelu_fast(acc[1] + wb.y), wv4[ct].y, accw);
      accw = fmaf(gelu_fast(acc[2] + wb.z), wv4[ct].z, accw);
      accw = fmaf(gelu_fast(acc[3] + wb.w), wv4[ct].w, accw);
    }
    accw += __shfl_xor(accw, 16, 64);
    accw += __shfl_xor(accw, 32, 64);
    if (quad == 0 && valid) logw[(size_t)b * 1024 + gp] = accw + bw2v;
  }
}

// ================= K4: softmax stats + threshold-select ~top-128 candidates =================
__global__ __launch_bounds__(256) void k4_select(
    const float* __restrict__ logw, int* __restrict__ selidx,
    float* __restrict__ selval, float* __restrict__ mZ)
{
  __shared__ float fred[4];
  __shared__ float fredb[4];
  __shared__ int icnt[4];
  __shared__ int cpos;
  const int tid = threadIdx.x;
  const int wv = tid >> 6;
  const int ln = tid & 63;
  const int b = blockIdx.x;

  float v[4], vm[4];
  #pragma unroll
  for (int j = 0; j < 4; ++j) {
    int n = tid + j * 256;
    bool real = (n < NP);
    float x = real ? logw[(size_t)b * 1024 + n] : -1e30f;
    v[j] = x;
    vm[j] = real ? x : 1e30f;
  }
  float mx = fmaxf(fmaxf(v[0], v[1]), fmaxf(v[2], v[3]));
  float mnl = fminf(fminf(vm[0], vm[1]), fminf(vm[2], vm[3]));
  #pragma unroll
  for (int off = 1; off < 64; off <<= 1) {
    mx = fmaxf(mx, __shfl_xor(mx, off, 64));
    mnl = fminf(mnl, __shfl_xor(mnl, off, 64));
  }
  if (ln == 0) { fred[wv] = mx; fredb[wv] = mnl; }
  __syncthreads();
  const float m = fmaxf(fmaxf(fred[0], fred[1]), fmaxf(fred[2], fred[3]));
  const float mn = fminf(fminf(fredb[0], fredb[1]), fminf(fredb[2], fredb[3]));

  float s = expf(v[0] - m) + expf(v[1] - m) + expf(v[2] - m) + expf(v[3] - m);
  #pragma unroll
  for (int off = 1; off < 64; off <<= 1) s += __shfl_xor(s, off, 64);
  __syncthreads();
  if (ln == 0) fred[wv] = s;
  __syncthreads();
  if (tid == 0) {
    mZ[b * 2 + 0] = m;
    mZ[b * 2 + 1] = fred[0] + fred[1] + fred[2] + fred[3];
  }

  float lo = mn, hi = m;
  float tsel = 0.f;
  bool found = false;
  for (int it = 0; it < 28; ++it) {
    float t = 0.5f * (lo + hi);
    if (!(t > lo && t < hi)) break;
    int c = (v[0] >= t) + (v[1] >= t) + (v[2] >= t) + (v[3] >= t);
    #pragma unroll
    for (int off = 1; off < 64; off <<= 1) c += __shfl_xor(c, off, 64);
    __syncthreads();
    if (ln == 0) icnt[wv] = c;
    __syncthreads();
    int cnt = icnt[0] + icnt[1] + icnt[2] + icnt[3];
    if (cnt > CAND) lo = t;
    else if (cnt <= 96) hi = t;
    else { tsel = t; found = true; break; }
  }
  if (!found) tsel = hi;

  if (tid == 0) cpos = 0;
  __syncthreads();
  #pragma unroll
  for (int j = 0; j < 4; ++j) {
    int n = tid + j * 256;
    if (n < NP && v[j] >= tsel) {
      int pp = atomicAdd(&cpos, 1);
      if (pp < CAND) {
        selidx[b * CAND + pp] = n;
        selval[b * CAND + pp] = v[j];
      }
    }
  }
  __syncthreads();
  if (tid == 0) {
    int cc = cpos < CAND ? cpos : CAND;
    for (int i2 = cc; i2 < CAND; ++i2) {
      selidx[b * CAND + i2] = -1;
      selval[b * CAND + i2] = -1e30f;
    }
  }
}

// ================= K5: exact fp32 recompute of candidates (fused) =================
__global__ __launch_bounds__(256, 1) void k5_recompute(
    const float* __restrict__ X, const float* __restrict__ W1Tf,
    const float* __restrict__ Wt2, const float* __restrict__ W3Tf,
    const float* __restrict__ Ww2, const float* __restrict__ bw2,
    const float* __restrict__ bt2, const float* __restrict__ tbias,
    const float* __restrict__ wbias, const int* __restrict__ selidx,
    float* __restrict__ lwc, float* __restrict__ Pc)
{
  __shared__ __align__(16) float W1L[8192];   // 32 KB
  __shared__ __align__(16) float W2L[8192];   // 32 KB
  const int tid = threadIdx.x;

  #pragma unroll
  for (int it = 0; it < 8; ++it) {
    int i = tid + it * 256;
    ((float4*)W1L)[i] = ((const float4*)W1Tf)[i];
    ((float4*)W2L)[i] = ((const float4*)Wt2)[i];
  }
  __syncthreads();

  const int gc = blockIdx.x * 256 + tid;               // global candidate id
  const int b = __builtin_amdgcn_readfirstlane(gc >> 7);  // wave-uniform
  const int c = gc & (CAND - 1);
  const int pidx = selidx[b * CAND + c];
  const int pj = pidx < 0 ? 0 : pidx;
  const float xs = pidx < 0 ? 0.f : 0.1f;

  float x[64];
  {
    const float* xr = X + (size_t)b * (NP * 64) + (size_t)pj * 64;
    #pragma unroll
    for (int d4 = 0; d4 < 16; ++d4) {
      float4 vv = *(const float4*)(xr + d4 * 4);
      x[d4 * 4 + 0] = xs * vv.x; x[d4 * 4 + 1] = xs * vv.y;
      x[d4 * 4 + 2] = xs * vv.z; x[d4 * 4 + 3] = xs * vv.w;
    }
  }
  float p[64];
  #pragma unroll
  for (int d4 = 0; d4 < 16; ++d4) {
    float4 vv = *(const float4*)(bt2 + d4 * 4);
    p[d4 * 4 + 0] = vv.x; p[d4 * 4 + 1] = vv.y;
    p[d4 * 4 + 2] = vv.z; p[d4 * 4 + 3] = vv.w;
  }

  const float* tb = tbias + b * 128;   // uniform base -> s_load per j
  #pragma unroll 2
  for (int j = 0; j < 128; ++j) {
    const float* wr = &W1L[j * 64];
    float a0 = 0.f, a1 = 0.f, a2 = 0.f, a3 = 0.f;
    #pragma unroll
    for (int d = 0; d < 64; d += 4) {
      a0 = fmaf(x[d + 0], wr[d + 0], a0);
      a1 = fmaf(x[d + 1], wr[d + 1], a1);
      a2 = fmaf(x[d + 2], wr[d + 2], a2);
      a3 = fmaf(x[d + 3], wr[d + 3], a3);
    }
    float h = gelu_ex(tb[j] + ((a0 + a1) + (a2 + a3)));
    const float* w2r = &W2L[j * 64];
    #pragma unroll
    for (int d = 0; d < 64; ++d) p[d] = fmaf(h, w2r[d], p[d]);
  }

  float* pout = Pc + (size_t)gc * 64;
  #pragma unroll
  for (int d4 = 0; d4 < 16; ++d4) {
    *(float4*)(pout + d4 * 4) =
        make_float4(p[d4 * 4], p[d4 * 4 + 1], p[d4 * 4 + 2], p[d4 * 4 + 3]);
  }

  __syncthreads();
  // re-stage W3 (16 KB) over W1L, Ww2 over W2L
  #pragma unroll
  for (int it = 0; it < 4; ++it) {
    int i = tid + it * 256;
    ((float4*)W1L)[i] = ((const float4*)W3Tf)[i];
  }
  if (tid < 64) W2L[tid] = Ww2[tid];
  __syncthreads();

  const float* wb = wbias + b * 64;    // uniform base -> s_load per j
  float lw = bw2[0];
  #pragma unroll 2
  for (int j = 0; j < 64; ++j) {
    const float* w3r = &W1L[j * 64];
    float a0 = 0.f, a1 = 0.f, a2 = 0.f, a3 = 0.f;
    #pragma unroll
    for (int d = 0; d < 64; d += 4) {
      a0 = fmaf(p[d + 0], w3r[d + 0], a0);
      a1 = fmaf(p[d + 1], w3r[d + 1], a1);
      a2 = fmaf(p[d + 2], w3r[d + 2], a2);
      a3 = fmaf(p[d + 3], w3r[d + 3], a3);
    }
    lw = fmaf(gelu_ex(wb[j] + ((a0 + a1) + (a2 + a3))), W2L[j], lw);
  }
  lwc[b * CAND + c] = (pidx < 0) ? -1e30f : lw;
}

// ================= K5c: exact top-32 + weighted gather =================
__global__ __launch_bounds__(128) void k5c_final(
    const float* __restrict__ lwc, const int* __restrict__ selidx,
    const float* __restrict__ selval, const float* __restrict__ mZ,
    const float* __restrict__ Pc, float* __restrict__ out0)
{
  __shared__ unsigned long long wk[2];
  __shared__ float zc[2];
  __shared__ float selw[32];
  __shared__ int selc[32];
  __shared__ float part[2][64];
  const int tid = threadIdx.x;
  const int wv = tid >> 6;
  const int ln = tid & 63;
  const int b = blockIdx.x;
  const float m = mZ[b * 2 + 0];
  const float Z = mZ[b * 2 + 1];
  const int c = tid;
  const float v = lwc[b * CAND + c];
  const int pidx = selidx[b * CAND + c];
  const float sv = selval[b * CAND + c];

  float corr = expf(v - m) - expf(sv - m);
  float cs = corr;
  #pragma unroll
  for (int off = 1; off < 64; off <<= 1) cs += __shfl_xor(cs, off, 64);
  if (ln == 0) zc[wv] = cs;
  __syncthreads();
  const float Zadj = Z + zc[0] + zc[1];

  unsigned u;
  { union { float f; unsigned uu; } q; q.f = v; u = q.uu; }
  u = ((int)u < 0) ? ~u : (u | 0x80000000u);
  unsigned pid_u = (pidx >= 0) ? (unsigned)pidx : 0xFFFFFFFEu;
  unsigned long long key = ((unsigned long long)u << 32) | (unsigned)(~pid_u);

  for (int round = 0; round < 32; ++round) {
    unsigned long long bk = key;
    #pragma unroll
    for (int off = 1; off < 64; off <<= 1) {
      unsigned long long o = __shfl_xor(bk, off, 64);
      bk = o > bk ? o : bk;
    }
    if (ln == 0) wk[wv] = bk;
    __syncthreads();
    unsigned long long best = wk[0] > wk[1] ? wk[0] : wk[1];
    if (key == best) {
      selw[round] = expf(v - m) / Zadj;
      selc[round] = c;
      key = 0ull;
    }
    __syncthreads();
  }

  {
    const int d = ln;
    float acc = 0.f;
    const float* Pb = Pc + (size_t)b * CAND * 64;
    #pragma unroll
    for (int r = 0; r < 16; ++r) {
      int rr = wv * 16 + r;
      acc += selw[rr] * Pb[(size_t)selc[rr] * 64 + d];
    }
    part[wv][d] = acc;
    __syncthreads();
    if (tid < 64) out0[b * 64 + tid] = part[0][tid] + part[1][tid];
  }
}

// ================= launch =================
extern "C" void kernel_launch(void* const* d_in, const int* in_sizes, int n_in,
                              void* d_out, int out_size, void* d_ws, size_t ws_size,
                              hipStream_t stream)
{
  const float* obs = (const float*)d_in[0];
  const float* X   = (const float*)d_in[1];
  const float* Wo1 = (const float*)d_in[2];
  const float* bo1 = (const float*)d_in[3];
  const float* Wo2 = (const float*)d_in[4];
  const float* bo2 = (const float*)d_in[5];
  const float* Wt1 = (const float*)d_in[6];
  const float* bt1 = (const float*)d_in[7];
  const float* Wt2 = (const float*)d_in[8];
  const float* bt2 = (const float*)d_in[9];
  const float* Ww1 = (const float*)d_in[10];
  const float* bw1 = (const float*)d_in[11];
  const float* Ww2 = (const float*)d_in[12];
  const float* bw2 = (const float*)d_in[13];
  const float* Wr  = (const float*)d_in[14];
  const float* br  = (const float*)d_in[15];

  float* out0 = (float*)d_out;
  float* out1 = (float*)d_out + 2048 * 64;

  char* ws = (char*)d_ws;
  unsigned short* W1T = (unsigned short*)(ws + OFF_W1T);
  unsigned short* W2T = (unsigned short*)(ws + OFF_W2T);
  unsigned short* W3T = (unsigned short*)(ws + OFF_W3T);
  float* W1Tf   = (float*)(ws + OFF_W1TF);
  float* W3Tf   = (float*)(ws + OFF_W3TF);
  float* tbias  = (float*)(ws + OFF_TB);
  float* wbias  = (float*)(ws + OFF_WB);
  float* logw   = (float*)(ws + OFF_LOGW);
  int*   sidx   = (int*)(ws + OFF_SIDX);
  float* sval   = (float*)(ws + OFF_SVAL);
  float* mZ     = (float*)(ws + OFF_MZ);
  float* lwc    = (float*)(ws + OFF_LWC);
  float* Pc     = (float*)(ws + OFF_PC);

  k0_prep<<<128, 256, 0, stream>>>(Wt1, Wt2, Ww1, W1T, W2T, W3T, W1Tf, W3Tf);
  k1_mean<<<2048, 256, 0, stream>>>(X, Wr, br, Wt1, bt1, tbias, out1);
  k2_obs<<<2048, 128, 0, stream>>>(obs, Wo1, bo1, Wo2, bo2, Ww1, bw1, wbias);
  k3_main<<<dim3(4, 2048), 256, 0, stream>>>(X, W1T, W2T, W3T, tbias, wbias,
                                             bt2, Ww2, bw2, logw);
  k4_select<<<2048, 256, 0, stream>>>(logw, sidx, sval, mZ);
  k5_recompute<<<1024, 256, 0, stream>>>(X, W1Tf, Wt2, W3Tf, Ww2, bw2,
                                         bt2, tbias, wbias, sidx, lwc, Pc);
  k5c_final<<<2048, 128, 0, stream>>>(lwc, sidx, sval, mZ, Pc, out0);
}